// Round 1
// baseline (2488.879 us; speedup 1.0000x reference)
//
#include <hip/hip_runtime.h>
#include <math.h>

#define BATCH 1024
#define SEQ   144
#define DIM   192
#define NH    6
#define HD    32
#define SCALE 0.17677669529663687f  // 1/sqrt(32)

// ---------------------------------------------------------------------------
// Kernel A: combined bias+mask table  biasm[h][i][j] = bias_table[pidx[i][j]][h]
//           + (mask[i][j]==0 ? -1e9 : 0)
// ---------------------------------------------------------------------------
__global__ void k_bias(const float* __restrict__ bt, const int* __restrict__ pidx,
                       const int* __restrict__ mask, float* __restrict__ biasm) {
    int idx = blockIdx.x * blockDim.x + threadIdx.x;
    if (idx >= SEQ * SEQ) return;
    int p = pidx[idx];
    float m = (mask[idx] == 0) ? -1e9f : 0.0f;
#pragma unroll
    for (int h = 0; h < NH; ++h)
        biasm[h * SEQ * SEQ + idx] = bt[p * NH + h] + m;
}

// ---------------------------------------------------------------------------
// Kernel B: per (b,h) fused  qkv-projection -> S = q k^T *scale + bias ->
//           softmax -> out = S v   (out layout [B, N, H*HD] = pre-projection)
// 512 threads (8 waves). LDS ~137 KB -> 1 block/CU, 2 waves/SIMD.
// ---------------------------------------------------------------------------
__global__ __launch_bounds__(512) void k_attn(
        const float* __restrict__ x, const float* __restrict__ w1,
        const float* __restrict__ b1, const float* __restrict__ biasm,
        float* __restrict__ out) {
    // S region (83520 B) doubles as GEMM staging during phase 1
    __shared__ float smem[SEQ * (SEQ + 1)];
    __shared__ float q_s[SEQ][HD + 1];
    __shared__ float k_s[SEQ][HD + 1];
    __shared__ float v_s[SEQ][HD];

    const int b = blockIdx.x / NH;
    const int h = blockIdx.x % NH;
    const int tid = threadIdx.x;

    // ---- Phase 1: qkv = x[b] @ w1[:, cols(h)] + b1   ([144 x 96], K=192)
    // thread grid 16 rows x 32 cols: rows ty+16a (a<9), cols tx+32c (c<3)
    {
        const int ty = tid >> 5;          // 0..15
        const int tx = tid & 31;          // 0..31
        float acc[9][3];
#pragma unroll
        for (int a = 0; a < 9; ++a)
#pragma unroll
            for (int c = 0; c < 3; ++c) acc[a][c] = 0.f;

        float (*x_c)[33] = (float(*)[33])smem;                 // [144][33]
        float (*w_c)[96] = (float(*)[96])(smem + SEQ * 33);    // [32][96]
        const float* xb = x + (size_t)b * SEQ * DIM;

        for (int ck = 0; ck < 6; ++ck) {
            __syncthreads();   // protect previous chunk's reads
            for (int idx = tid; idx < SEQ * 32; idx += 512) {
                int n = idx >> 5, kk = idx & 31;
                x_c[n][kk] = xb[n * DIM + ck * 32 + kk];
            }
            for (int idx = tid; idx < 32 * 96; idx += 512) {
                int kk = idx / 96, c = idx % 96;
                int t = c >> 5, j = c & 31;
                w_c[kk][c] = w1[(ck * 32 + kk) * 576 + t * 192 + h * 32 + j];
            }
            __syncthreads();
#pragma unroll
            for (int kk = 0; kk < 32; ++kk) {
                float xa[9], wb[3];
#pragma unroll
                for (int a = 0; a < 9; ++a) xa[a] = x_c[ty + 16 * a][kk];
#pragma unroll
                for (int c = 0; c < 3; ++c) wb[c] = w_c[kk][tx + 32 * c];
#pragma unroll
                for (int a = 0; a < 9; ++a)
#pragma unroll
                    for (int c = 0; c < 3; ++c) acc[a][c] += xa[a] * wb[c];
            }
        }
        __syncthreads();
        // scatter to q/k/v (scale folded into q)
#pragma unroll
        for (int c = 0; c < 3; ++c) {
            int col = tx + 32 * c;
            int t = col >> 5, j = col & 31;
            float bb = b1[t * 192 + h * 32 + j];
#pragma unroll
            for (int a = 0; a < 9; ++a) {
                int row = ty + 16 * a;
                float val = acc[a][c] + bb;
                if (t == 0)      q_s[row][j] = val * SCALE;
                else if (t == 1) k_s[row][j] = val;
                else             v_s[row][j] = val;
            }
        }
        __syncthreads();
    }

    // ---- Phase 2: S = q k^T + biasm  (4x4 register tiles over 36x36 tiles)
    {
        float* S_s = smem;   // [144][145]
        const float* bm = biasm + h * SEQ * SEQ;
        for (int tile = tid; tile < 36 * 36; tile += 512) {
            int i0 = (tile / 36) * 4, j0 = (tile % 36) * 4;
            float sa[4][4];
#pragma unroll
            for (int a = 0; a < 4; ++a)
#pragma unroll
                for (int c = 0; c < 4; ++c)
                    sa[a][c] = bm[(i0 + a) * SEQ + j0 + c];
#pragma unroll
            for (int kk = 0; kk < 32; ++kk) {
                float qa[4], kb[4];
#pragma unroll
                for (int a = 0; a < 4; ++a) qa[a] = q_s[i0 + a][kk];
#pragma unroll
                for (int c = 0; c < 4; ++c) kb[c] = k_s[j0 + c][kk];
#pragma unroll
                for (int a = 0; a < 4; ++a)
#pragma unroll
                    for (int c = 0; c < 4; ++c) sa[a][c] += qa[a] * kb[c];
            }
#pragma unroll
            for (int a = 0; a < 4; ++a)
#pragma unroll
                for (int c = 0; c < 4; ++c)
                    S_s[(i0 + a) * (SEQ + 1) + j0 + c] = sa[a][c];
        }
        __syncthreads();
    }

    // ---- Phase 3: softmax, one wave per row (8 waves x 18 rows)
    {
        float* S_s = smem;
        const int wave = tid >> 6, lane = tid & 63;
        for (int r = wave; r < SEQ; r += 8) {
            float* row = S_s + r * (SEQ + 1);
            float v0 = row[lane];
            float v1 = row[lane + 64];
            bool has2 = (lane + 128) < SEQ;
            float v2 = has2 ? row[lane + 128] : -1e30f;
            float mx = fmaxf(fmaxf(v0, v1), v2);
#pragma unroll
            for (int off = 32; off; off >>= 1) mx = fmaxf(mx, __shfl_xor(mx, off));
            float e0 = __expf(v0 - mx), e1 = __expf(v1 - mx);
            float e2 = has2 ? __expf(v2 - mx) : 0.f;
            float s = e0 + e1 + e2;
#pragma unroll
            for (int off = 32; off; off >>= 1) s += __shfl_xor(s, off);
            float inv = 1.f / s;
            row[lane] = e0 * inv;
            row[lane + 64] = e1 * inv;
            if (has2) row[lane + 128] = e2 * inv;
        }
        __syncthreads();
    }

    // ---- Phase 4: out = S @ v  -> d_out[b][i][h*32+jd]
    {
        float* S_s = smem;
        const int jd = tid & 31;
        const int i_base = tid >> 5;   // 0..15
        for (int step = 0; step < 9; ++step) {
            int i = i_base + step * 16;
            float accp = 0.f;
#pragma unroll 4
            for (int j = 0; j < SEQ; ++j)
                accp += S_s[i * (SEQ + 1) + j] * v_s[j][jd];
            out[((size_t)b * SEQ + i) * DIM + h * HD + jd] = accp;
        }
    }
}

// ---------------------------------------------------------------------------
// Kernel C: in-place output projection  out = out @ w2 + b2
// 256 threads, 32 rows/block. Rows staged to LDS before overwrite.
// ---------------------------------------------------------------------------
__global__ __launch_bounds__(256) void k_proj(
        float* __restrict__ out, const float* __restrict__ w2,
        const float* __restrict__ b2) {
    __shared__ float in_s[32][DIM + 1];
    __shared__ float w_s[32][DIM];
    const int tid = threadIdx.x;
    const int ty = tid >> 4, tx = tid & 15;
    const size_t m0 = (size_t)blockIdx.x * 32;

    for (int idx = tid; idx < 32 * DIM; idx += 256)
        in_s[idx / DIM][idx % DIM] = out[m0 * DIM + idx];

    float acc[2][12];
#pragma unroll
    for (int a = 0; a < 2; ++a)
#pragma unroll
        for (int c = 0; c < 12; ++c) acc[a][c] = 0.f;

    for (int ck = 0; ck < 6; ++ck) {
        __syncthreads();   // in_s visible (ck=0) / previous w_s reads done
        for (int idx = tid; idx < 32 * DIM; idx += 256) {
            int kk = idx / DIM, c = idx % DIM;
            w_s[kk][c] = w2[(ck * 32 + kk) * DIM + c];
        }
        __syncthreads();
#pragma unroll
        for (int kk = 0; kk < 32; ++kk) {
            float xa[2], wb[12];
            xa[0] = in_s[ty][ck * 32 + kk];
            xa[1] = in_s[ty + 16][ck * 32 + kk];
#pragma unroll
            for (int c = 0; c < 12; ++c) wb[c] = w_s[kk][tx + 16 * c];
#pragma unroll
            for (int a = 0; a < 2; ++a)
#pragma unroll
                for (int c = 0; c < 12; ++c) acc[a][c] += xa[a] * wb[c];
        }
    }
#pragma unroll
    for (int a = 0; a < 2; ++a)
#pragma unroll
        for (int c = 0; c < 12; ++c) {
            int col = tx + 16 * c;
            out[(m0 + ty + 16 * a) * DIM + col] = acc[a][c] + b2[col];
        }
}

// ---------------------------------------------------------------------------
extern "C" void kernel_launch(void* const* d_in, const int* in_sizes, int n_in,
                              void* d_out, int out_size, void* d_ws, size_t ws_size,
                              hipStream_t stream) {
    const float* x    = (const float*)d_in[0];
    const float* w1   = (const float*)d_in[1];
    const float* b1   = (const float*)d_in[2];
    const float* w2   = (const float*)d_in[3];
    const float* b2   = (const float*)d_in[4];
    const float* bt   = (const float*)d_in[5];
    const int*   pidx = (const int*)d_in[6];
    const int*   mask = (const int*)d_in[7];
    float* out   = (float*)d_out;
    float* biasm = (float*)d_ws;   // 6*144*144 floats = 497664 B

    k_bias<<<(SEQ * SEQ + 255) / 256, 256, 0, stream>>>(bt, pidx, mask, biasm);
    k_attn<<<BATCH * NH, 512, 0, stream>>>(x, w1, b1, biasm, out);
    k_proj<<<(BATCH * SEQ) / 32, 256, 0, stream>>>(out, w2, b2);
}

// Round 2
// 416.247 us; speedup vs baseline: 5.9793x; 5.9793x over previous
//
#include <hip/hip_runtime.h>

#define BATCH 1024
#define SEQ   144
#define DIM   192
#define NH    6
#define HD    32
#define SCALE 0.17677669529663687f  // 1/sqrt(32)

typedef __bf16 bf16x8 __attribute__((ext_vector_type(8)));
typedef __bf16 bf16x4 __attribute__((ext_vector_type(4)));
typedef float  f32x4  __attribute__((ext_vector_type(4)));

// ---- workspace layout (bytes) ----
#define WS_W1T   0         // bf16 [576][192]  w1t[c][k] = w1[k][c] (*SCALE for c<192)
#define WS_W2T   221184    // bf16 [192][192]  w2t[n][k] = w2[k][n]
#define WS_B1S   294912    // f32  [576]       b1 (*SCALE for c<192)
#define WS_BIAS  297216    // f32  [6][144][144]  bmT[h][n][m] = bias[h][m][n] + mask
// total: 794880 B

// ---------------------------------------------------------------------------
// Prep: transpose/convert weights to bf16 B^T layout, build bias+mask table.
// Exact ranges: 432 blocks w1t, 144 w2t, 81 bias, 1 b1s  (grid = 658 x 256).
// ---------------------------------------------------------------------------
__global__ __launch_bounds__(256) void k_prep(
        const float* __restrict__ w1, const float* __restrict__ w2,
        const float* __restrict__ b1, const float* __restrict__ bt,
        const int* __restrict__ pidx, const int* __restrict__ mask,
        char* __restrict__ ws) {
    __bf16* w1t = (__bf16*)(ws + WS_W1T);
    __bf16* w2t = (__bf16*)(ws + WS_W2T);
    float*  b1s = (float*)(ws + WS_B1S);
    float*  bm  = (float*)(ws + WS_BIAS);
    const int blk = blockIdx.x, t = threadIdx.x;
    if (blk < 432) {                       // w1t: 110592 elems
        int idx = blk * 256 + t;
        int k = idx / 576, c = idx % 576;
        float v = w1[idx] * (c < 192 ? SCALE : 1.0f);
        w1t[c * 192 + k] = (__bf16)v;
    } else if (blk < 576) {                // w2t: 36864 elems
        int idx = (blk - 432) * 256 + t;
        int k = idx / 192, n = idx % 192;
        w2t[n * 192 + k] = (__bf16)w2[idx];
    } else if (blk < 657) {                // biasT: 20736 positions
        int idx = (blk - 576) * 256 + t;
        int m = idx / 144, n = idx % 144;
        int p = pidx[idx];
        float add = (mask[idx] == 0) ? -1e9f : 0.0f;
#pragma unroll
        for (int h = 0; h < NH; ++h)
            bm[(h * 144 + n) * 144 + m] = bt[p * NH + h] + add;
    } else {                               // b1s
        for (int c = t; c < 576; c += 256)
            b1s[c] = b1[c] * (c < 192 ? SCALE : 1.0f);
    }
}

// ---------------------------------------------------------------------------
// Main: one block per b. 576 threads = 9 waves; wave w owns M-strip [16w,16w+16).
// Per head: QKV-proj (MFMA) -> swapped QK^T (MFMA) + in-register softmax ->
// PV (MFMA) -> out-proj partial (MFMA) accumulated in registers across heads.
// LDS regions overlaid by lifetime; all strides 2-way-bank-conflict-free.
// ---------------------------------------------------------------------------
__global__ __launch_bounds__(576, 3) void k_attn(
        const float* __restrict__ x, const char* __restrict__ ws,
        const float* __restrict__ b2, float* __restrict__ out) {
    const __bf16* w1t = (const __bf16*)(ws + WS_W1T);
    const __bf16* w2t = (const __bf16*)(ws + WS_W2T);
    const float*  b1s = (const float*)(ws + WS_B1S);
    const float*  bmT = (const float*)(ws + WS_BIAS);

    // Region map (bytes):  A:Xs[144][200] @0 | B:Ws[96][200]|Ps[144][168] @57600
    // C:Qs[144][40]|Os[144][40] @105984 | D:Ks[144][40] @117504
    // E:Vt[32][168]|W2s[192][40] @129024   -> total 144384
    __shared__ char smem[144384];
    __bf16* Xs  = (__bf16*)(smem);
    __bf16* WB  = (__bf16*)(smem + 57600);
    __bf16* QO  = (__bf16*)(smem + 105984);
    __bf16* Ks  = (__bf16*)(smem + 117504);
    __bf16* VW  = (__bf16*)(smem + 129024);

    const int b   = blockIdx.x;
    const int tid = threadIdx.x;
    const int w   = tid >> 6;          // wave 0..8
    const int lr  = tid & 15;          // lane row within frag
    const int lg  = (tid & 63) >> 4;   // lane group 0..3
    const int m0  = w * 16;

    // ---- phase 0: stage X[b] fp32 -> bf16 LDS [144][200]
    {
        const f32x4* x4 = (const f32x4*)(x + (size_t)b * SEQ * DIM);
#pragma unroll
        for (int it = 0; it < 12; ++it) {
            int i = tid + it * 576;                 // 6912 float4 chunks total
            f32x4 v = x4[i];
            int row = i / 48, col = (i % 48) * 4;
            bf16x4 pk;
            pk[0] = (__bf16)v[0]; pk[1] = (__bf16)v[1];
            pk[2] = (__bf16)v[2]; pk[3] = (__bf16)v[3];
            *(bf16x4*)&Xs[row * 200 + col] = pk;
        }
    }

    f32x4 outacc[12];
#pragma unroll
    for (int n = 0; n < 12; ++n) outacc[n] = (f32x4){0.f, 0.f, 0.f, 0.f};

    const f32x4 zf = {0.f, 0.f, 0.f, 0.f};

    for (int h = 0; h < NH; ++h) {
        __syncthreads();   // prev head's region reads all done

        // ---- stage Ws[96][200]: row r=t*32+j <- w1t[t*192+h*32+j][0..192)
        {
            __bf16* Ws = WB;
#pragma unroll
            for (int it = 0; it < 4; ++it) {
                int idx = tid + it * 576;           // 2304 16B chunks
                int r = idx / 24, c = idx % 24;
                int tt = r >> 5, j = r & 31;
                bf16x8 v = *(const bf16x8*)(w1t + ((tt * 192 + h * 32 + j) * 192 + c * 8));
                *(bf16x8*)&Ws[r * 200 + c * 8] = v;
            }
        }
        __syncthreads();

        // ---- phase 1: Y[144][96] = Xs @ Ws^T ; scatter to Qs,Ks,Vt
        {
            __bf16* Ws = WB;
            __bf16* Qs = QO;
            __bf16* Vt = VW;
            f32x4 acc[6];
#pragma unroll
            for (int n = 0; n < 6; ++n) acc[n] = zf;
#pragma unroll
            for (int kk = 0; kk < 6; ++kk) {
                bf16x8 aF = *(bf16x8*)&Xs[(m0 + lr) * 200 + kk * 32 + lg * 8];
#pragma unroll
                for (int n = 0; n < 6; ++n) {
                    bf16x8 bF = *(bf16x8*)&Ws[(n * 16 + lr) * 200 + kk * 32 + lg * 8];
                    acc[n] = __builtin_amdgcn_mfma_f32_16x16x32_bf16(aF, bF, acc[n], 0, 0, 0);
                }
            }
#pragma unroll
            for (int n = 0; n < 6; ++n) {
                int cc = n * 16 + lr;                       // 0..95
                float bb = b1s[(n >> 1) * 192 + h * 32 + (cc & 31)];
                if (n < 2) {
#pragma unroll
                    for (int r = 0; r < 4; ++r)
                        Qs[(m0 + lg * 4 + r) * 40 + (cc & 31)] = (__bf16)(acc[n][r] + bb);
                } else if (n < 4) {
#pragma unroll
                    for (int r = 0; r < 4; ++r)
                        Ks[(m0 + lg * 4 + r) * 40 + (cc & 31)] = (__bf16)(acc[n][r] + bb);
                } else {
                    bf16x4 pk;
#pragma unroll
                    for (int r = 0; r < 4; ++r) pk[r] = (__bf16)(acc[n][r] + bb);
                    *(bf16x4*)&Vt[(cc & 31) * 168 + m0 + lg * 4] = pk;   // transposed
                }
            }
            // zero-pad Vt cols [144,160)
            if (tid < 128) {
                int j = tid >> 2, c = 144 + (tid & 3) * 4;
                *(bf16x4*)&Vt[j * 168 + c] = (bf16x4){(__bf16)0.f, (__bf16)0.f, (__bf16)0.f, (__bf16)0.f};
            }
        }
        __syncthreads();

        // ---- phase 2: S^T = mfma(K, Q) ; +bias ; softmax in regs ; P -> Ps bf16
        {
            __bf16* Qs = QO;
            __bf16* Ps = WB;
            const float* bmh = bmT + h * SEQ * SEQ;
            const int m = m0 + lr;                   // this lane's query row
            bf16x8 qF = *(bf16x8*)&Qs[(m0 + lr) * 40 + lg * 8];
            f32x4 st[9];
#pragma unroll
            for (int i = 0; i < 9; ++i) {
                bf16x8 aF = *(bf16x8*)&Ks[(i * 16 + lr) * 40 + lg * 8];
                st[i] = __builtin_amdgcn_mfma_f32_16x16x32_bf16(aF, qF, zf, 0, 0, 0);
            }
            float mx = -3.0e38f;
#pragma unroll
            for (int i = 0; i < 9; ++i)
#pragma unroll
                for (int r = 0; r < 4; ++r) {
                    st[i][r] += bmh[(i * 16 + lg * 4 + r) * 144 + m];
                    mx = fmaxf(mx, st[i][r]);
                }
            mx = fmaxf(mx, __shfl_xor(mx, 16));
            mx = fmaxf(mx, __shfl_xor(mx, 32));
            float sum = 0.f;
#pragma unroll
            for (int i = 0; i < 9; ++i)
#pragma unroll
                for (int r = 0; r < 4; ++r) {
                    float e = __expf(st[i][r] - mx);
                    st[i][r] = e;
                    sum += e;
                }
            sum += __shfl_xor(sum, 16);
            sum += __shfl_xor(sum, 32);
            float inv = 1.f / sum;
#pragma unroll
            for (int i = 0; i < 9; ++i) {
                bf16x4 pk;
#pragma unroll
                for (int r = 0; r < 4; ++r) pk[r] = (__bf16)(st[i][r] * inv);
                *(bf16x4*)&Ps[m * 168 + i * 16 + lg * 4] = pk;
            }
            // zero-pad P cols [144,160) for this wave's rows
            *(bf16x4*)&Ps[m * 168 + 144 + lg * 4] =
                (bf16x4){(__bf16)0.f, (__bf16)0.f, (__bf16)0.f, (__bf16)0.f};
        }
        __syncthreads();

        // ---- phase 3: O = P @ V   (K = 160 incl. zero pad, 5 steps)
        {
            __bf16* Ps = WB;
            __bf16* Vt = VW;
            __bf16* Os = QO;
            f32x4 o0 = zf, o1 = zf;
#pragma unroll
            for (int s = 0; s < 5; ++s) {
                bf16x8 aF = *(bf16x8*)&Ps[(m0 + lr) * 168 + s * 32 + lg * 8];
                bf16x8 b0 = *(bf16x8*)&Vt[lr * 168 + s * 32 + lg * 8];
                bf16x8 b1v = *(bf16x8*)&Vt[(16 + lr) * 168 + s * 32 + lg * 8];
                o0 = __builtin_amdgcn_mfma_f32_16x16x32_bf16(aF, b0, o0, 0, 0, 0);
                o1 = __builtin_amdgcn_mfma_f32_16x16x32_bf16(aF, b1v, o1, 0, 0, 0);
            }
#pragma unroll
            for (int r = 0; r < 4; ++r) {
                Os[(m0 + lg * 4 + r) * 40 + lr]      = (__bf16)o0[r];
                Os[(m0 + lg * 4 + r) * 40 + 16 + lr] = (__bf16)o1[r];
            }
        }
        __syncthreads();

        // ---- stage W2s[192][40]: rows n, cols k = h*32..h*32+31
        {
            __bf16* W2s = VW;
            for (int idx = tid; idx < 768; idx += 576) {
                int row = idx >> 2, c = idx & 3;
                bf16x8 v = *(const bf16x8*)(w2t + (row * 192 + h * 32 + c * 8));
                *(bf16x8*)&W2s[row * 40 + c * 8] = v;
            }
        }
        __syncthreads();

        // ---- phase 4: outacc += O_h @ W2[h*32:(h+1)*32, :]
        {
            __bf16* Os = QO;
            __bf16* W2s = VW;
            bf16x8 aF = *(bf16x8*)&Os[(m0 + lr) * 40 + lg * 8];
#pragma unroll
            for (int n = 0; n < 12; ++n) {
                bf16x8 bF = *(bf16x8*)&W2s[(n * 16 + lr) * 40 + lg * 8];
                outacc[n] = __builtin_amdgcn_mfma_f32_16x16x32_bf16(aF, bF, outacc[n], 0, 0, 0);
            }
        }
    }

    // ---- epilogue: + b2, store fp32 (coalesced 64B runs)
#pragma unroll
    for (int n = 0; n < 12; ++n) {
        int col = n * 16 + lr;
        float bb = b2[col];
#pragma unroll
        for (int r = 0; r < 4; ++r) {
            int m = m0 + lg * 4 + r;
            out[((size_t)b * SEQ + m) * DIM + col] = outacc[n][r] + bb;
        }
    }
}

// ---------------------------------------------------------------------------
extern "C" void kernel_launch(void* const* d_in, const int* in_sizes, int n_in,
                              void* d_out, int out_size, void* d_ws, size_t ws_size,
                              hipStream_t stream) {
    const float* x    = (const float*)d_in[0];
    const float* w1   = (const float*)d_in[1];
    const float* b1   = (const float*)d_in[2];
    const float* w2   = (const float*)d_in[3];
    const float* b2   = (const float*)d_in[4];
    const float* bt   = (const float*)d_in[5];
    const int*   pidx = (const int*)d_in[6];
    const int*   mask = (const int*)d_in[7];
    float* out = (float*)d_out;
    char*  ws  = (char*)d_ws;

    k_prep<<<658, 256, 0, stream>>>(w1, w2, b1, bt, pidx, mask, ws);
    k_attn<<<BATCH, 576, 0, stream>>>(x, ws, b2, out);
}